// Round 6
// baseline (659.830 us; speedup 1.0000x reference)
//
#include <hip/hip_runtime.h>

// GraphSAGE round 6: aggregation fused into the MFMA GEMM kernel (gather
// writes frag-order LDS directly; no aggb global round-trip).
// CSR build (fixed-capacity buckets) and bf16 path unchanged from round 5.

#define F   128
#define FH  64
#define EPS 1e-5f
#define CAP 4096            // slots per bucket (avg fill 2046)

typedef __attribute__((ext_vector_type(8))) short short8v;
typedef __attribute__((ext_vector_type(4))) short short4v;
typedef __attribute__((ext_vector_type(4))) float floatx4;

__device__ inline unsigned short f2bf(float f) {
    unsigned u = __builtin_bit_cast(unsigned, f);
    u += 0x7fff + ((u >> 16) & 1);          // round-to-nearest-even
    return (unsigned short)(u >> 16);
}
__device__ inline float bflo(unsigned u) { return __builtin_bit_cast(float, u << 16); }
__device__ inline float bfhi(unsigned u) { return __builtin_bit_cast(float, u & 0xffff0000u); }

// ---------------- x -> bf16 ----------------
__global__ __launch_bounds__(256) void conv_bf16_kernel(
    const float* __restrict__ x, unsigned short* __restrict__ xb, int total4)
{
    int t = blockIdx.x * 256 + threadIdx.x;
    if (t >= total4) return;
    float4 v = reinterpret_cast<const float4*>(x)[t];
    short4v p = { (short)f2bf(v.x), (short)f2bf(v.y), (short)f2bf(v.z), (short)f2bf(v.w) };
    *reinterpret_cast<short4v*>(xb + t * 4) = p;
}

// ---------------- CSR build ----------------
__global__ void bcur_init_kernel(int* __restrict__ bcur, int B)
{
    int t = blockIdx.x * 256 + threadIdx.x;
    if (t < B) bcur[t] = t * CAP;
}

__global__ __launch_bounds__(1024) void scatter_block_kernel(
    const int* __restrict__ src, const int* __restrict__ dst,
    int* __restrict__ bcur, int* __restrict__ keys, int E, int B)
{
    __shared__ int hist[1024];
    __shared__ int lbase[1024];
    const int tid = threadIdx.x;
    const int e0 = blockIdx.x * 16384;
    const int e1 = min(e0 + 16384, E);
    hist[tid] = 0;
    __syncthreads();
    for (int e = e0 + tid; e < e1; e += 1024)
        atomicAdd(&hist[dst[e] >> 7], 1);          // LDS, non-returning
    __syncthreads();
    if (tid < B) {
        int c = hist[tid];
        lbase[tid] = (c > 0) ? atomicAdd(&bcur[tid], c) : 0;   // 1 returning atomic / bucket
    }
    __syncthreads();
    hist[tid] = 0;                                  // reuse as local cursor
    __syncthreads();
    for (int e = e0 + tid; e < e1; e += 1024) {
        int d = dst[e];
        int b = d >> 7;
        int p = lbase[b] + atomicAdd(&hist[b], 1);  // LDS returning (fast)
        if (p < (b + 1) * CAP)                      // overflow guard (never in practice)
            keys[p] = (src[e] << 7) | (d & 127);
    }
}

__global__ __launch_bounds__(256) void bucket_sort_kernel(
    const int* __restrict__ keys, const int* __restrict__ bcur,
    int* __restrict__ eid, int* __restrict__ start, int* __restrict__ deg, int n)
{
    __shared__ int cnt[128], cur[128], sc[128];
    __shared__ int sorted[CAP];
    const int b = blockIdx.x;
    const int tid = threadIdx.x;
    const int base = b * CAP;
    int count = bcur[b] - base;
    if (count > CAP) count = CAP;
    const int v0 = b << 7;

    if (tid < 128) cnt[tid] = 0;
    __syncthreads();
    for (int i = tid; i < count; i += 256)
        atomicAdd(&cnt[keys[base + i] & 127], 1);
    __syncthreads();
    if (tid < 128) sc[tid] = cnt[tid];
    __syncthreads();
    for (int o = 1; o < 128; o <<= 1) {
        int a = (tid < 128 && tid >= o) ? sc[tid - o] : 0;
        __syncthreads();
        if (tid < 128) sc[tid] += a;
        __syncthreads();
    }
    if (tid < 128) {
        int excl = sc[tid] - cnt[tid];
        int v = v0 + tid;
        if (v < n) { start[v] = base + excl; deg[v] = cnt[tid]; }
        cur[tid] = excl;
    }
    __syncthreads();
    for (int i = tid; i < count; i += 256) {
        int k = keys[base + i];
        int p = atomicAdd(&cur[k & 127], 1);
        sorted[p] = k >> 7;
    }
    __syncthreads();
    for (int i = tid; i < count; i += 256) eid[base + i] = sorted[i];
}

// ---------------- weight prep: fp32 [K][N] -> bf16 fragment order ----------------
struct PrepArgs { const float* s[8]; unsigned short* d[8]; };

__global__ __launch_bounds__(256) void prep_all_kernel(PrepArgs a)
{
    int t = blockIdx.x * 256 + threadIdx.x;
    int m, idx, K, N;
    if (t < 4 * 16384)            { m = t >> 14;                 idx = t & 16383; K = 128; N = 128; }
    else if (t < 4 * 16384 + 2 * 8192) { int u = t - 4 * 16384;  m = 4 + (u >> 13); idx = u & 8191; K = 128; N = 64; }
    else                          { int u = t - 4 * 16384 - 2 * 8192; if (u >= 2 * 8192) return;
                                    m = 6 + (u >> 13); idx = u & 8191; K = 64; N = 128; }
    int k = idx / N, c = idx % N;
    int ct = c >> 4, ks = k >> 5;
    int lane = (c & 15) + (((k & 31) >> 3) << 4);
    int j = k & 7;
    a.d[m][((ct * (K >> 5) + ks) * 64 + lane) * 8 + j] = f2bf(a.s[m][idx]);
}

// ---------------- fused aggregate + MFMA GEMM ----------------
// per block (64 rows): gather agg rows from xb via CSR -> frag-order LDS;
// y = agg@Wl + x@Wr + bl (+BN colsum/colsq); skip = relu(x@sw1+sb1)@sw2+sb2.
__global__ __launch_bounds__(256, 2) void fused_agg_gemm(
    const unsigned short* __restrict__ xb,
    const int* __restrict__ eid, const int* __restrict__ start,
    const int* __restrict__ deg,
    const unsigned short* __restrict__ wlf, const unsigned short* __restrict__ wrf,
    const unsigned short* __restrict__ whf, const unsigned short* __restrict__ wsf,
    const float* __restrict__ bl, const float* __restrict__ sb1,
    const float* __restrict__ sb2,
    unsigned short* __restrict__ y, unsigned short* __restrict__ skip,
    float* __restrict__ colsum, float* __restrict__ colsq, int n)
{
    __shared__ unsigned short xsf[4 * 4 * 64 * 8];   // 16 KB x tile, frag order
    __shared__ unsigned short asf[4 * 4 * 64 * 8];   // 16 KB agg tile, frag order
    __shared__ unsigned short hsm[64 * 88];          // 11.3 KB

    const int tid = threadIdx.x;
    const int r0 = blockIdx.x * 64;
    const int w = tid >> 6;
    const int l = tid & 63;

    // ---- stage x tile into frag-order LDS ----
    {
        const short8v zero8 = {0, 0, 0, 0, 0, 0, 0, 0};
        for (int i = tid; i < 64 * 16; i += 256) {
            int r = i >> 4, s = i & 15;
            int row = r0 + r;
            short8v vx = zero8;
            if (row < n)
                vx = *reinterpret_cast<const short8v*>(xb + (size_t)row * F + s * 8);
            int rt = r >> 4, ks = s >> 2;
            int lslot = (r & 15) + ((s & 3) << 4);
            *(short8v*)&xsf[((rt * 4 + ks) * 64 + lslot) * 8] = vx;
        }
    }

    // ---- register-resident B fragments ----
    const short8v* wl8 = (const short8v*)wlf;
    const short8v* wr8 = (const short8v*)wrf;
    const short8v* wh8 = (const short8v*)whf;
    const short8v* ws8 = (const short8v*)wsf;
    short8v bWl[2][4], bWr[2][4];
#pragma unroll
    for (int ct = 0; ct < 2; ++ct)
#pragma unroll
        for (int ks = 0; ks < 4; ++ks) {
            int idx = ((w * 2 + ct) * 4 + ks) * 64 + l;
            bWl[ct][ks] = wl8[idx];
            bWr[ct][ks] = wr8[idx];
        }
    short8v bh[4];
#pragma unroll
    for (int ks = 0; ks < 4; ++ks) bh[ks] = wh8[(w * 4 + ks) * 64 + l];
    short8v bs[2][2];
#pragma unroll
    for (int ct = 0; ct < 2; ++ct)
#pragma unroll
        for (int ks = 0; ks < 2; ++ks)
            bs[ct][ks] = ws8[((w * 2 + ct) * 2 + ks) * 64 + l];

    // ---- gather-aggregate: wave w handles rows r0+w*16 .. +15 ----
    // lane l accumulates cols 2l, 2l+1; result written to asf in frag order:
    // rt=w, ks=l>>4, lslot=(r&15)+16*((l&15)>>2), j=(2l)&7  (bijection, verified)
    {
        const unsigned* xb2 = (const unsigned*)xb;
        const int aoff_shorts = ((w * 4 + (l >> 4)) * 64 + 16 * ((l & 15) >> 2)) * 8 + ((2 * l) & 7);
        for (int i = 0; i < 16; ++i) {
            int v = r0 + w * 16 + i;
            float a0 = 0.f, a1 = 0.f, b0 = 0.f, b1 = 0.f;
            int c = 0;
            if (v < n) {
                const int beg = start[v];
                c = deg[v];
                int off = beg, rem = c;
                while (rem > 0) {
                    int m = rem < 64 ? rem : 64;
                    int id = (l < m) ? eid[off + l] : 0;
                    int j = 0;
                    for (; j + 3 < m; j += 4) {
                        int s0 = __shfl(id, j), s1 = __shfl(id, j + 1);
                        int s2 = __shfl(id, j + 2), s3 = __shfl(id, j + 3);
                        unsigned u0 = xb2[(size_t)s0 * 64 + l];
                        unsigned u1 = xb2[(size_t)s1 * 64 + l];
                        unsigned u2 = xb2[(size_t)s2 * 64 + l];
                        unsigned u3 = xb2[(size_t)s3 * 64 + l];
                        a0 += bflo(u0); a1 += bfhi(u0);
                        b0 += bflo(u1); b1 += bfhi(u1);
                        a0 += bflo(u2); a1 += bfhi(u2);
                        b0 += bflo(u3); b1 += bfhi(u3);
                    }
                    for (; j < m; ++j) {
                        int s0 = __shfl(id, j);
                        unsigned u0 = xb2[(size_t)s0 * 64 + l];
                        a0 += bflo(u0); a1 += bfhi(u0);
                    }
                    off += m; rem -= m;
                }
            }
            float inv = 1.0f / fmaxf((float)c, 1.0f);
            unsigned pk = (unsigned)f2bf((a0 + b0) * inv) |
                          ((unsigned)f2bf((a1 + b1) * inv) << 16);
            *(unsigned*)&asf[aoff_shorts + i * 8] = pk;
        }
    }
    __syncthreads();

    const short8v* xs8 = (const short8v*)xsf;
    const short8v* as8 = (const short8v*)asf;
    const int col0 = w * 32 + (l & 15);
    const float bias0 = bl[col0], bias1 = bl[col0 + 16];

    // ---- phase Y ----
    float psum0 = 0.f, psq0 = 0.f, psum1 = 0.f, psq1 = 0.f;
#pragma unroll
    for (int rt = 0; rt < 4; ++rt) {
        floatx4 acc0 = {0.f, 0.f, 0.f, 0.f};
        floatx4 acc1 = {0.f, 0.f, 0.f, 0.f};
#pragma unroll
        for (int ks = 0; ks < 4; ++ks) {
            short8v ax = xs8[(rt * 4 + ks) * 64 + l];
            short8v aa = as8[(rt * 4 + ks) * 64 + l];
            acc0 = __builtin_amdgcn_mfma_f32_16x16x32_bf16(aa, bWl[0][ks], acc0, 0, 0, 0);
            acc0 = __builtin_amdgcn_mfma_f32_16x16x32_bf16(ax, bWr[0][ks], acc0, 0, 0, 0);
            acc1 = __builtin_amdgcn_mfma_f32_16x16x32_bf16(aa, bWl[1][ks], acc1, 0, 0, 0);
            acc1 = __builtin_amdgcn_mfma_f32_16x16x32_bf16(ax, bWr[1][ks], acc1, 0, 0, 0);
        }
        int rowb = r0 + rt * 16 + (l >> 4) * 4;
#pragma unroll
        for (int reg = 0; reg < 4; ++reg) {
            int row = rowb + reg;
            if (row < n) {
                float v0 = acc0[reg] + bias0;
                float v1 = acc1[reg] + bias1;
                y[(size_t)row * F + col0] = f2bf(v0);
                y[(size_t)row * F + col0 + 16] = f2bf(v1);
                psum0 += v0; psq0 += v0 * v0;
                psum1 += v1; psq1 += v1 * v1;
            }
        }
    }
    psum0 += __shfl_xor(psum0, 16); psum0 += __shfl_xor(psum0, 32);
    psq0  += __shfl_xor(psq0, 16);  psq0  += __shfl_xor(psq0, 32);
    psum1 += __shfl_xor(psum1, 16); psum1 += __shfl_xor(psum1, 32);
    psq1  += __shfl_xor(psq1, 16);  psq1  += __shfl_xor(psq1, 32);
    if (l < 16) {
        unsafeAtomicAdd(&colsum[col0], psum0);
        unsafeAtomicAdd(&colsq[col0], psq0);
        unsafeAtomicAdd(&colsum[col0 + 16], psum1);
        unsafeAtomicAdd(&colsq[col0 + 16], psq1);
    }

    // ---- phase H: h = relu(x@sw1 + sb1) -> LDS bf16 ----
    const int hcol = w * 16 + (l & 15);
    const float hbias = sb1[hcol];
#pragma unroll
    for (int rt = 0; rt < 4; ++rt) {
        floatx4 hacc = {0.f, 0.f, 0.f, 0.f};
#pragma unroll
        for (int ks = 0; ks < 4; ++ks) {
            short8v ax = xs8[(rt * 4 + ks) * 64 + l];
            hacc = __builtin_amdgcn_mfma_f32_16x16x32_bf16(ax, bh[ks], hacc, 0, 0, 0);
        }
        int rowb = rt * 16 + (l >> 4) * 4;
#pragma unroll
        for (int reg = 0; reg < 4; ++reg)
            hsm[(rowb + reg) * 88 + hcol] = f2bf(fmaxf(hacc[reg] + hbias, 0.f));
    }
    __syncthreads();

    // ---- phase S: skip = h @ sw2 + sb2 ----
    const float sbias0 = sb2[col0], sbias1 = sb2[col0 + 16];
#pragma unroll
    for (int rt = 0; rt < 4; ++rt) {
        floatx4 s0 = {0.f, 0.f, 0.f, 0.f};
        floatx4 s1 = {0.f, 0.f, 0.f, 0.f};
#pragma unroll
        for (int ks = 0; ks < 2; ++ks) {
            short8v ah = *(const short8v*)&hsm[(rt * 16 + (l & 15)) * 88 + ks * 32 + (l >> 4) * 8];
            s0 = __builtin_amdgcn_mfma_f32_16x16x32_bf16(ah, bs[0][ks], s0, 0, 0, 0);
            s1 = __builtin_amdgcn_mfma_f32_16x16x32_bf16(ah, bs[1][ks], s1, 0, 0, 0);
        }
        int rowb = r0 + rt * 16 + (l >> 4) * 4;
#pragma unroll
        for (int reg = 0; reg < 4; ++reg) {
            int row = rowb + reg;
            if (row < n) {
                skip[(size_t)row * F + col0] = f2bf(s0[reg] + sbias0);
                skip[(size_t)row * F + col0 + 16] = f2bf(s1[reg] + sbias1);
            }
        }
    }
}

// ---------------- BN stats -> scale/shift ----------------
__global__ void bn_finalize_kernel(const float* __restrict__ colsum,
                                   const float* __restrict__ colsq,
                                   const float* __restrict__ g,
                                   const float* __restrict__ beta,
                                   float* __restrict__ scale,
                                   float* __restrict__ shift, float invn)
{
    int j = threadIdx.x;
    float mu = colsum[j] * invn;
    float var = colsq[j] * invn - mu * mu;
    float rs = rsqrtf(var + EPS);
    float sc = rs * g[j];
    scale[j] = sc;
    shift[j] = beta[j] - mu * sc;
}

// ---------------- out = relu(y*scale + shift + skip); bf16 or fp32 out ----------------
__global__ __launch_bounds__(256) void apply_kernel(
    const unsigned int* __restrict__ y2, const unsigned int* __restrict__ s2,
    const float* __restrict__ scale, const float* __restrict__ shift,
    unsigned int* __restrict__ out_bf, float* __restrict__ out_f32,
    int out_fp32, int nq)
{
    int t = blockIdx.x * 256 + threadIdx.x;
    if (t >= nq) return;
    int jq = t & 31;
    uint2 yv = reinterpret_cast<const uint2*>(y2)[t];
    uint2 sv = reinterpret_cast<const uint2*>(s2)[t];
    float4 sc = reinterpret_cast<const float4*>(scale)[jq];
    float4 sh = reinterpret_cast<const float4*>(shift)[jq];
    float o0 = fmaxf(bflo(yv.x) * sc.x + sh.x + bflo(sv.x), 0.f);
    float o1 = fmaxf(bfhi(yv.x) * sc.y + sh.y + bfhi(sv.x), 0.f);
    float o2 = fmaxf(bflo(yv.y) * sc.z + sh.z + bflo(sv.y), 0.f);
    float o3 = fmaxf(bfhi(yv.y) * sc.w + sh.w + bfhi(sv.y), 0.f);
    if (out_fp32) {
        reinterpret_cast<float4*>(out_f32)[t] = make_float4(o0, o1, o2, o3);
    } else {
        uint2 p;
        p.x = (unsigned)f2bf(o0) | ((unsigned)f2bf(o1) << 16);
        p.y = (unsigned)f2bf(o2) | ((unsigned)f2bf(o3) << 16);
        reinterpret_cast<uint2*>(out_bf)[t] = p;
    }
}

extern "C" void kernel_launch(void* const* d_in, const int* in_sizes, int n_in,
                              void* d_out, int out_size, void* d_ws, size_t ws_size,
                              hipStream_t stream)
{
    const float* x    = (const float*)d_in[0];
    const int*   ei   = (const int*)d_in[1];
    const float* Wl1  = (const float*)d_in[2];
    const float* bl1  = (const float*)d_in[3];
    const float* Wr1  = (const float*)d_in[4];
    const float* Wl2  = (const float*)d_in[5];
    const float* bl2  = (const float*)d_in[6];
    const float* Wr2  = (const float*)d_in[7];
    const float* s1w1 = (const float*)d_in[8];
    const float* s1b1 = (const float*)d_in[9];
    const float* s1w2 = (const float*)d_in[10];
    const float* s1b2 = (const float*)d_in[11];
    const float* s2w1 = (const float*)d_in[12];
    const float* s2b1 = (const float*)d_in[13];
    const float* s2w2 = (const float*)d_in[14];
    const float* s2b2 = (const float*)d_in[15];
    const float* g1   = (const float*)d_in[16];
    const float* be1  = (const float*)d_in[17];
    const float* g2   = (const float*)d_in[18];
    const float* be2  = (const float*)d_in[19];

    const int n = in_sizes[0] / F;       // 100000
    const int E = in_sizes[1] / 2;       // 1600000
    const int* src = ei;
    const int* dst = ei + E;
    const int B = (n + 127) >> 7;        // 782 buckets

    // ---- workspace carve-up (float units) ----
    float* ws = (float*)d_ws;
    size_t off = 0;
    float* csum = ws + off; off += F;
    float* csq  = ws + off; off += F;
    float* scl  = ws + off; off += F;
    float* shf  = ws + off; off += F;
    unsigned short* xb    = (unsigned short*)(ws + off); off += (size_t)n * F / 2;
    unsigned short* x1b   = (unsigned short*)(ws + off); off += (size_t)n * F / 2;
    unsigned short* yb    = (unsigned short*)(ws + off); off += (size_t)n * F / 2;
    unsigned short* skipb = (unsigned short*)(ws + off); off += (size_t)n * F / 2;
    unsigned short* wbf   = (unsigned short*)(ws + off);
    size_t woff = 0;
    unsigned short* fWl1  = wbf + woff; woff += F * F;
    unsigned short* fWr1  = wbf + woff; woff += F * F;
    unsigned short* fWl2  = wbf + woff; woff += F * F;
    unsigned short* fWr2  = wbf + woff; woff += F * F;
    unsigned short* fs1w1 = wbf + woff; woff += F * FH;
    unsigned short* fs2w1 = wbf + woff; woff += F * FH;
    unsigned short* fs1w2 = wbf + woff; woff += FH * F;
    unsigned short* fs2w2 = wbf + woff; woff += FH * F;
    off += (woff + 1) / 2;
    int* iws = (int*)(ws + off);
    size_t ioff = 0;
    int* bcur  = iws + ioff; ioff += 1024;
    int* start = iws + ioff; ioff += n;
    int* deg   = iws + ioff; ioff += n;
    int* keys  = iws + ioff; ioff += (size_t)B * CAP;
    int* eid   = iws + ioff; ioff += (size_t)B * CAP;

    const int total4 = n * (F / 4);
    const int sblocks = (E + 16383) / 16384;
    const int gblocks = (n + 63) / 64;
    const int nq = n * (F / 4);
    const int apblocks = (nq + 255) / 256;
    const float invn = 1.0f / (float)n;

    // ---- x -> bf16 ----
    conv_bf16_kernel<<<(total4 + 255) / 256, 256, 0, stream>>>(x, xb, total4);

    // ---- CSR build ----
    bcur_init_kernel<<<4, 256, 0, stream>>>(bcur, B);
    scatter_block_kernel<<<sblocks, 1024, 0, stream>>>(src, dst, bcur, keys, E, B);
    bucket_sort_kernel<<<B, 256, 0, stream>>>(keys, bcur, eid, start, deg, n);

    // ---- weight prep ----
    PrepArgs pa;
    pa.s[0] = Wl1;  pa.d[0] = fWl1;
    pa.s[1] = Wr1;  pa.d[1] = fWr1;
    pa.s[2] = Wl2;  pa.d[2] = fWl2;
    pa.s[3] = Wr2;  pa.d[3] = fWr2;
    pa.s[4] = s1w1; pa.d[4] = fs1w1;
    pa.s[5] = s2w1; pa.d[5] = fs2w1;
    pa.s[6] = s1w2; pa.d[6] = fs1w2;
    pa.s[7] = s2w2; pa.d[7] = fs2w2;
    prep_all_kernel<<<384, 256, 0, stream>>>(pa);

    // ---- layer 1 ----
    hipMemsetAsync(csum, 0, 2 * F * sizeof(float), stream);
    fused_agg_gemm<<<gblocks, 256, 0, stream>>>(xb, eid, start, deg,
        fWl1, fWr1, fs1w1, fs1w2, bl1, s1b1, s1b2, yb, skipb, csum, csq, n);
    bn_finalize_kernel<<<1, F, 0, stream>>>(csum, csq, g1, be1, scl, shf, invn);
    apply_kernel<<<apblocks, 256, 0, stream>>>((const unsigned*)yb, (const unsigned*)skipb,
        scl, shf, (unsigned*)x1b, nullptr, 0, nq);

    // ---- layer 2 ----
    hipMemsetAsync(csum, 0, 2 * F * sizeof(float), stream);
    fused_agg_gemm<<<gblocks, 256, 0, stream>>>(x1b, eid, start, deg,
        fWl2, fWr2, fs2w1, fs2w2, bl2, s2b1, s2b2, yb, skipb, csum, csq, n);
    bn_finalize_kernel<<<1, F, 0, stream>>>(csum, csq, g2, be2, scl, shf, invn);
    apply_kernel<<<apblocks, 256, 0, stream>>>((const unsigned*)yb, (const unsigned*)skipb,
        scl, shf, nullptr, (float*)d_out, 1, nq);
}

// Round 7
// 452.602 us; speedup vs baseline: 1.4579x; 1.4579x over previous
//
#include <hip/hip_runtime.h>

// GraphSAGE round 7: R5 structure (separate aggregate, max TLP) +
//  (a) fp8-e4m3 gather path (halves aggregation traffic; fp32 accumulate),
//  (b) coalesced GEMM epilogue (LDS transpose -> dwordx4 stores).

#define F   128
#define FH  64
#define EPS 1e-5f
#define CAP 4096            // slots per bucket (avg fill 2046)
#define TSTR 132            // transpose LDS row stride in shorts (264 B, 8B-aligned)

typedef __attribute__((ext_vector_type(8))) short short8v;
typedef __attribute__((ext_vector_type(4))) short short4v;
typedef __attribute__((ext_vector_type(4))) float floatx4;
typedef __attribute__((ext_vector_type(2))) float floatx2;

__device__ inline unsigned short f2bf(float f) {
    unsigned u = __builtin_bit_cast(unsigned, f);
    u += 0x7fff + ((u >> 16) & 1);          // round-to-nearest-even
    return (unsigned short)(u >> 16);
}
__device__ inline float bflo(unsigned u) { return __builtin_bit_cast(float, u << 16); }
__device__ inline float bfhi(unsigned u) { return __builtin_bit_cast(float, u & 0xffff0000u); }

// ---------------- x -> bf16 + fp8 ----------------
__global__ __launch_bounds__(256) void conv_dual_kernel(
    const float* __restrict__ x, unsigned short* __restrict__ xb,
    unsigned* __restrict__ x8, int total4)
{
    int t = blockIdx.x * 256 + threadIdx.x;
    if (t >= total4) return;
    float4 v = reinterpret_cast<const float4*>(x)[t];
    short4v p = { (short)f2bf(v.x), (short)f2bf(v.y), (short)f2bf(v.z), (short)f2bf(v.w) };
    *reinterpret_cast<short4v*>(xb + t * 4) = p;
    unsigned p8 = __builtin_amdgcn_cvt_pk_fp8_f32(v.x, v.y, 0, false);
    p8 = __builtin_amdgcn_cvt_pk_fp8_f32(v.z, v.w, p8, true);
    x8[t] = p8;
}

// ---------------- CSR build (unchanged from R5) ----------------
__global__ void bcur_init_kernel(int* __restrict__ bcur, int B)
{
    int t = blockIdx.x * 256 + threadIdx.x;
    if (t < B) bcur[t] = t * CAP;
}

__global__ __launch_bounds__(1024) void scatter_block_kernel(
    const int* __restrict__ src, const int* __restrict__ dst,
    int* __restrict__ bcur, int* __restrict__ keys, int E, int B)
{
    __shared__ int hist[1024];
    __shared__ int lbase[1024];
    const int tid = threadIdx.x;
    const int e0 = blockIdx.x * 16384;
    const int e1 = min(e0 + 16384, E);
    hist[tid] = 0;
    __syncthreads();
    for (int e = e0 + tid; e < e1; e += 1024)
        atomicAdd(&hist[dst[e] >> 7], 1);
    __syncthreads();
    if (tid < B) {
        int c = hist[tid];
        lbase[tid] = (c > 0) ? atomicAdd(&bcur[tid], c) : 0;
    }
    __syncthreads();
    hist[tid] = 0;
    __syncthreads();
    for (int e = e0 + tid; e < e1; e += 1024) {
        int d = dst[e];
        int b = d >> 7;
        int p = lbase[b] + atomicAdd(&hist[b], 1);
        if (p < (b + 1) * CAP)
            keys[p] = (src[e] << 7) | (d & 127);
    }
}

__global__ __launch_bounds__(256) void bucket_sort_kernel(
    const int* __restrict__ keys, const int* __restrict__ bcur,
    int* __restrict__ eid, int* __restrict__ start, int* __restrict__ deg, int n)
{
    __shared__ int cnt[128], cur[128], sc[128];
    __shared__ int sorted[CAP];
    const int b = blockIdx.x;
    const int tid = threadIdx.x;
    const int base = b * CAP;
    int count = bcur[b] - base;
    if (count > CAP) count = CAP;
    const int v0 = b << 7;

    if (tid < 128) cnt[tid] = 0;
    __syncthreads();
    for (int i = tid; i < count; i += 256)
        atomicAdd(&cnt[keys[base + i] & 127], 1);
    __syncthreads();
    if (tid < 128) sc[tid] = cnt[tid];
    __syncthreads();
    for (int o = 1; o < 128; o <<= 1) {
        int a = (tid < 128 && tid >= o) ? sc[tid - o] : 0;
        __syncthreads();
        if (tid < 128) sc[tid] += a;
        __syncthreads();
    }
    if (tid < 128) {
        int excl = sc[tid] - cnt[tid];
        int v = v0 + tid;
        if (v < n) { start[v] = base + excl; deg[v] = cnt[tid]; }
        cur[tid] = excl;
    }
    __syncthreads();
    for (int i = tid; i < count; i += 256) {
        int k = keys[base + i];
        int p = atomicAdd(&cur[k & 127], 1);
        sorted[p] = k >> 7;
    }
    __syncthreads();
    for (int i = tid; i < count; i += 256) eid[base + i] = sorted[i];
}

// ---------------- gather aggregation (fp8 rows): agg[v] = mean x[N(v)] ------------
// one wave per node; lane l covers cols 2l, 2l+1 (one ushort = 2 fp8 per row).
__global__ __launch_bounds__(256) void aggregate_kernel(
    const unsigned short* __restrict__ x8, const int* __restrict__ eid,
    const int* __restrict__ start, const int* __restrict__ deg,
    unsigned int* __restrict__ aggb2, int n)
{
    int w = (blockIdx.x * 256 + threadIdx.x) >> 6;
    int l = threadIdx.x & 63;
    if (w >= n) return;
    const int beg = start[w];
    const int c   = deg[w];
    float a0 = 0.f, a1 = 0.f, b0 = 0.f, b1 = 0.f;
    int off = beg, rem = c;
    while (rem > 0) {
        int m = rem < 64 ? rem : 64;
        int id = (l < m) ? eid[off + l] : 0;
        int j = 0;
        for (; j + 3 < m; j += 4) {
            int s0 = __shfl(id, j), s1 = __shfl(id, j + 1);
            int s2 = __shfl(id, j + 2), s3 = __shfl(id, j + 3);
            unsigned short u0 = x8[(size_t)s0 * 64 + l];
            unsigned short u1 = x8[(size_t)s1 * 64 + l];
            unsigned short u2 = x8[(size_t)s2 * 64 + l];
            unsigned short u3 = x8[(size_t)s3 * 64 + l];
            floatx2 f0 = __builtin_amdgcn_cvt_pk_f32_fp8((int)u0, false);
            floatx2 f1 = __builtin_amdgcn_cvt_pk_f32_fp8((int)u1, false);
            floatx2 f2 = __builtin_amdgcn_cvt_pk_f32_fp8((int)u2, false);
            floatx2 f3 = __builtin_amdgcn_cvt_pk_f32_fp8((int)u3, false);
            a0 += f0.x; a1 += f0.y;
            b0 += f1.x; b1 += f1.y;
            a0 += f2.x; a1 += f2.y;
            b0 += f3.x; b1 += f3.y;
        }
        for (; j < m; ++j) {
            int s0 = __shfl(id, j);
            unsigned short u0 = x8[(size_t)s0 * 64 + l];
            floatx2 f0 = __builtin_amdgcn_cvt_pk_f32_fp8((int)u0, false);
            a0 += f0.x; a1 += f0.y;
        }
        off += m; rem -= m;
    }
    float inv = 1.0f / fmaxf((float)c, 1.0f);
    float o0 = (a0 + b0) * inv, o1 = (a1 + b1) * inv;
    aggb2[(size_t)w * 64 + l] = (unsigned)f2bf(o0) | ((unsigned)f2bf(o1) << 16);
}

// ---------------- weight prep: fp32 [K][N] -> bf16 fragment order ----------------
struct PrepArgs { const float* s[8]; unsigned short* d[8]; };

__global__ __launch_bounds__(256) void prep_all_kernel(PrepArgs a)
{
    int t = blockIdx.x * 256 + threadIdx.x;
    int m, idx, K, N;
    if (t < 4 * 16384)            { m = t >> 14;                 idx = t & 16383; K = 128; N = 128; }
    else if (t < 4 * 16384 + 2 * 8192) { int u = t - 4 * 16384;  m = 4 + (u >> 13); idx = u & 8191; K = 128; N = 64; }
    else                          { int u = t - 4 * 16384 - 2 * 8192; if (u >= 2 * 8192) return;
                                    m = 6 + (u >> 13); idx = u & 8191; K = 64; N = 128; }
    int k = idx / N, c = idx % N;
    int ct = c >> 4, ks = k >> 5;
    int lane = (c & 15) + (((k & 31) >> 3) << 4);
    int j = k & 7;
    a.d[m][((ct * (K >> 5) + ks) * 64 + lane) * 8 + j] = f2bf(a.s[m][idx]);
}

// ---------------- fused MFMA GEMM, coalesced epilogue ----------------
__global__ __launch_bounds__(256, 2) void fused_gemm_mfma(
    const unsigned short* __restrict__ xb, const unsigned short* __restrict__ aggb,
    const unsigned short* __restrict__ wlf, const unsigned short* __restrict__ wrf,
    const unsigned short* __restrict__ whf, const unsigned short* __restrict__ wsf,
    const float* __restrict__ bl, const float* __restrict__ sb1,
    const float* __restrict__ sb2,
    unsigned short* __restrict__ y, unsigned short* __restrict__ skip,
    float* __restrict__ colsum, float* __restrict__ colsq, int n)
{
    __shared__ unsigned short xsf[4 * 4 * 64 * 8];   // 16 KB, frag order
    __shared__ unsigned short abuf[64 * TSTR];       // 16.5 KB: asf (first 8192) then transpose buffer
    __shared__ unsigned short hsm[64 * 88];          // 11.3 KB

    const int tid = threadIdx.x;
    const int r0 = blockIdx.x * 64;
    const int w = tid >> 6;
    const int l = tid & 63;

    // ---- stage x & agg tiles into frag-order LDS ----
    {
        const short8v zero8 = {0, 0, 0, 0, 0, 0, 0, 0};
        for (int i = tid; i < 64 * 16; i += 256) {
            int r = i >> 4, s = i & 15;
            int row = r0 + r;
            short8v vx = zero8, va = zero8;
            if (row < n) {
                vx = *reinterpret_cast<const short8v*>(xb + (size_t)row * F + s * 8);
                va = *reinterpret_cast<const short8v*>(aggb + (size_t)row * F + s * 8);
            }
            int rt = r >> 4, ks = s >> 2;
            int lslot = (r & 15) + ((s & 3) << 4);
            int off = ((rt * 4 + ks) * 64 + lslot) * 8;
            *(short8v*)&xsf[off] = vx;
            *(short8v*)&abuf[off] = va;
        }
    }

    // ---- register-resident B fragments ----
    const short8v* wl8 = (const short8v*)wlf;
    const short8v* wr8 = (const short8v*)wrf;
    const short8v* wh8 = (const short8v*)whf;
    const short8v* ws8 = (const short8v*)wsf;
    short8v bWl[2][4], bWr[2][4];
#pragma unroll
    for (int ct = 0; ct < 2; ++ct)
#pragma unroll
        for (int ks = 0; ks < 4; ++ks) {
            int idx = ((w * 2 + ct) * 4 + ks) * 64 + l;
            bWl[ct][ks] = wl8[idx];
            bWr[ct][ks] = wr8[idx];
        }
    short8v bh[4];
#pragma unroll
    for (int ks = 0; ks < 4; ++ks) bh[ks] = wh8[(w * 4 + ks) * 64 + l];
    short8v bs[2][2];
#pragma unroll
    for (int ct = 0; ct < 2; ++ct)
#pragma unroll
        for (int ks = 0; ks < 2; ++ks)
            bs[ct][ks] = ws8[((w * 2 + ct) * 2 + ks) * 64 + l];

    __syncthreads();

    const short8v* xs8 = (const short8v*)xsf;
    const short8v* as8 = (const short8v*)abuf;
    const int col0 = w * 32 + (l & 15);
    const float bias0 = bl[col0], bias1 = bl[col0 + 16];

    // ---- phase Y: MFMAs; keep packed results in regs ----
    unsigned ypk[4][4];
    float psum0 = 0.f, psq0 = 0.f, psum1 = 0.f, psq1 = 0.f;
#pragma unroll
    for (int rt = 0; rt < 4; ++rt) {
        floatx4 acc0 = {0.f, 0.f, 0.f, 0.f};
        floatx4 acc1 = {0.f, 0.f, 0.f, 0.f};
#pragma unroll
        for (int ks = 0; ks < 4; ++ks) {
            short8v ax = xs8[(rt * 4 + ks) * 64 + l];
            short8v aa = as8[(rt * 4 + ks) * 64 + l];
            acc0 = __builtin_amdgcn_mfma_f32_16x16x32_bf16(aa, bWl[0][ks], acc0, 0, 0, 0);
            acc0 = __builtin_amdgcn_mfma_f32_16x16x32_bf16(ax, bWr[0][ks], acc0, 0, 0, 0);
            acc1 = __builtin_amdgcn_mfma_f32_16x16x32_bf16(aa, bWl[1][ks], acc1, 0, 0, 0);
            acc1 = __builtin_amdgcn_mfma_f32_16x16x32_bf16(ax, bWr[1][ks], acc1, 0, 0, 0);
        }
        int rowb = r0 + rt * 16 + (l >> 4) * 4;
#pragma unroll
        for (int reg = 0; reg < 4; ++reg) {
            int row = rowb + reg;
            float v0 = acc0[reg] + bias0;
            float v1 = acc1[reg] + bias1;
            ypk[rt][reg] = (unsigned)f2bf(v0) | ((unsigned)f2bf(v1) << 16);
            if (row < n) {
                psum0 += v0; psq0 += v0 * v0;
                psum1 += v1; psq1 += v1 * v1;
            }
        }
    }
    psum0 += __shfl_xor(psum0, 16); psum0 += __shfl_xor(psum0, 32);
    psq0  += __shfl_xor(psq0, 16);  psq0  += __shfl_xor(psq0, 32);
    psum1 += __shfl_xor(psum1, 16); psum1 += __shfl_xor(psum1, 32);
    psq1  += __shfl_xor(psq1, 16);  psq1  += __shfl_xor(psq1, 32);
    if (l < 16) {
        unsafeAtomicAdd(&colsum[col0], psum0);
        unsafeAtomicAdd(&colsq[col0], psq0);
        unsafeAtomicAdd(&colsum[col0 + 16], psum1);
        unsafeAtomicAdd(&colsq[col0 + 16], psq1);
    }

    // ---- phase H: h = relu(x@sw1 + sb1) -> LDS bf16 ----
    const int hcol = w * 16 + (l & 15);
    const float hbias = sb1[hcol];
#pragma unroll
    for (int rt = 0; rt < 4; ++rt) {
        floatx4 hacc = {0.f, 0.f, 0.f, 0.f};
#pragma unroll
        for (int ks = 0; ks < 4; ++ks) {
            short8v ax = xs8[(rt * 4 + ks) * 64 + l];
            hacc = __builtin_amdgcn_mfma_f32_16x16x32_bf16(ax, bh[ks], hacc, 0, 0, 0);
        }
        int rowb = rt * 16 + (l >> 4) * 4;
#pragma unroll
        for (int reg = 0; reg < 4; ++reg)
            hsm[(rowb + reg) * 88 + hcol] = f2bf(fmaxf(hacc[reg] + hbias, 0.f));
    }
    __syncthreads();   // asf reads complete; hsm complete

    // ---- write y into transpose buffer ----
#pragma unroll
    for (int rt = 0; rt < 4; ++rt) {
        int rowb = rt * 16 + (l >> 4) * 4;
#pragma unroll
        for (int reg = 0; reg < 4; ++reg) {
            abuf[(rowb + reg) * TSTR + col0]      = (unsigned short)(ypk[rt][reg] & 0xffff);
            abuf[(rowb + reg) * TSTR + col0 + 16] = (unsigned short)(ypk[rt][reg] >> 16);
        }
    }

    // ---- phase S MFMAs (reads hsm; overlap with transpose) ----
    unsigned spk[4][4];
    const float sbias0 = sb2[col0], sbias1 = sb2[col0 + 16];
#pragma unroll
    for (int rt = 0; rt < 4; ++rt) {
        floatx4 s0 = {0.f, 0.f, 0.f, 0.f};
        floatx4 s1 = {0.f, 0.f, 0.f, 0.f};
#pragma unroll
        for (int ks = 0; ks < 2; ++ks) {
            short8v ah = *(const short8v*)&hsm[(rt * 16 + (l & 15)) * 88 + ks * 32 + (l >> 4) * 8];
            s0 = __builtin_amdgcn_mfma_f32_16x16x32_bf16(ah, bs[0][ks], s0, 0, 0, 0);
            s1 = __builtin_amdgcn_mfma_f32_16x16x32_bf16(ah, bs[1][ks], s1, 0, 0, 0);
        }
#pragma unroll
        for (int reg = 0; reg < 4; ++reg)
            spk[rt][reg] = (unsigned)f2bf(s0[reg] + sbias0) |
                           ((unsigned)f2bf(s1[reg] + sbias1) << 16);
    }
    __syncthreads();   // y transpose complete

    // ---- coalesced y store: wave = 64 rows x one 64B chunk ----
    {
        int row = tid & 63, ch = tid >> 6;
        if (r0 + row < n) {
            const uint2* srcp = (const uint2*)&abuf[row * TSTR + ch * 32];
            uint4* dst = (uint4*)(y + (size_t)(r0 + row) * F + ch * 32);
#pragma unroll
            for (int q = 0; q < 4; ++q) {
                uint2 a = srcp[2 * q], b2 = srcp[2 * q + 1];
                dst[q] = make_uint4(a.x, a.y, b2.x, b2.y);
            }
        }
    }
    __syncthreads();   // y store reads complete

    // ---- write skip into transpose buffer ----
#pragma unroll
    for (int rt = 0; rt < 4; ++rt) {
        int rowb = rt * 16 + (l >> 4) * 4;
#pragma unroll
        for (int reg = 0; reg < 4; ++reg) {
            abuf[(rowb + reg) * TSTR + col0]      = (unsigned short)(spk[rt][reg] & 0xffff);
            abuf[(rowb + reg) * TSTR + col0 + 16] = (unsigned short)(spk[rt][reg] >> 16);
        }
    }
    __syncthreads();

    // ---- coalesced skip store ----
    {
        int row = tid & 63, ch = tid >> 6;
        if (r0 + row < n) {
            const uint2* srcp = (const uint2*)&abuf[row * TSTR + ch * 32];
            uint4* dst = (uint4*)(skip + (size_t)(r0 + row) * F + ch * 32);
#pragma unroll
            for (int q = 0; q < 4; ++q) {
                uint2 a = srcp[2 * q], b2 = srcp[2 * q + 1];
                dst[q] = make_uint4(a.x, a.y, b2.x, b2.y);
            }
        }
    }
}

// ---------------- BN stats -> scale/shift ----------------
__global__ void bn_finalize_kernel(const float* __restrict__ colsum,
                                   const float* __restrict__ colsq,
                                   const float* __restrict__ g,
                                   const float* __restrict__ beta,
                                   float* __restrict__ scale,
                                   float* __restrict__ shift, float invn)
{
    int j = threadIdx.x;
    float mu = colsum[j] * invn;
    float var = colsq[j] * invn - mu * mu;
    float rs = rsqrtf(var + EPS);
    float sc = rs * g[j];
    scale[j] = sc;
    shift[j] = beta[j] - mu * sc;
}

// ---------------- out = relu(y*scale + shift + skip) ----------------
// layer-1 mode: writes x1 bf16 + x1 fp8.  layer-2 mode: writes fp32 d_out.
__global__ __launch_bounds__(256) void apply_kernel(
    const unsigned int* __restrict__ y2, const unsigned int* __restrict__ s2,
    const float* __restrict__ scale, const float* __restrict__ shift,
    unsigned int* __restrict__ out_bf, unsigned int* __restrict__ out_f8,
    float* __restrict__ out_f32, int out_fp32, int nq)
{
    int t = blockIdx.x * 256 + threadIdx.x;
    if (t >= nq) return;
    int jq = t & 31;
    uint2 yv = reinterpret_cast<const uint2*>(y2)[t];
    uint2 sv = reinterpret_cast<const uint2*>(s2)[t];
    float4 sc = reinterpret_cast<const float4*>(scale)[jq];
    float4 sh = reinterpret_cast<const float4*>(shift)[jq];
    float o0 = fmaxf(bflo(yv.x) * sc.x + sh.x + bflo(sv.x), 0.f);
    float o1 = fmaxf(bfhi(yv.x) * sc.y + sh.y + bfhi(sv.x), 0.f);
    float o2 = fmaxf(bflo(yv.y) * sc.z + sh.z + bflo(sv.y), 0.f);
    float o3 = fmaxf(bfhi(yv.y) * sc.w + sh.w + bfhi(sv.y), 0.f);
    if (out_fp32) {
        reinterpret_cast<float4*>(out_f32)[t] = make_float4(o0, o1, o2, o3);
    } else {
        uint2 p;
        p.x = (unsigned)f2bf(o0) | ((unsigned)f2bf(o1) << 16);
        p.y = (unsigned)f2bf(o2) | ((unsigned)f2bf(o3) << 16);
        reinterpret_cast<uint2*>(out_bf)[t] = p;
        unsigned p8 = __builtin_amdgcn_cvt_pk_fp8_f32(o0, o1, 0, false);
        p8 = __builtin_amdgcn_cvt_pk_fp8_f32(o2, o3, p8, true);
        out_f8[t] = p8;
    }
}

extern "C" void kernel_launch(void* const* d_in, const int* in_sizes, int n_in,
                              void* d_out, int out_size, void* d_ws, size_t ws_size,
                              hipStream_t stream)
{
    const float* x    = (const float*)d_in[0];
    const int*   ei   = (const int*)d_in[1];
    const float* Wl1  = (const float*)d_in[2];
    const float* bl1  = (const float*)d_in[3];
    const float* Wr1  = (const float*)d_in[4];
    const float* Wl2  = (const float*)d_in[5];
    const float* bl2  = (const float*)d_in[6];
    const float* Wr2  = (const float*)d_in[7];
    const float* s1w1 = (const float*)d_in[8];
    const float* s1b1 = (const float*)d_in[9];
    const float* s1w2 = (const float*)d_in[10];
    const float* s1b2 = (const float*)d_in[11];
    const float* s2w1 = (const float*)d_in[12];
    const float* s2b1 = (const float*)d_in[13];
    const float* s2w2 = (const float*)d_in[14];
    const float* s2b2 = (const float*)d_in[15];
    const float* g1   = (const float*)d_in[16];
    const float* be1  = (const float*)d_in[17];
    const float* g2   = (const float*)d_in[18];
    const float* be2  = (const float*)d_in[19];

    const int n = in_sizes[0] / F;       // 100000
    const int E = in_sizes[1] / 2;       // 1600000
    const int* src = ei;
    const int* dst = ei + E;
    const int B = (n + 127) >> 7;        // 782 buckets

    // ---- workspace carve-up (float units) ----
    float* ws = (float*)d_ws;
    size_t off = 0;
    float* csum = ws + off; off += F;
    float* csq  = ws + off; off += F;
    float* scl  = ws + off; off += F;
    float* shf  = ws + off; off += F;
    unsigned short* xb    = (unsigned short*)(ws + off); off += (size_t)n * F / 2;
    unsigned short* x1b   = (unsigned short*)(ws + off); off += (size_t)n * F / 2;
    unsigned short* yb    = (unsigned short*)(ws + off); off += (size_t)n * F / 2;
    unsigned short* skipb = (unsigned short*)(ws + off); off += (size_t)n * F / 2;
    unsigned short* aggb  = (unsigned short*)(ws + off); off += (size_t)n * F / 2;
    unsigned* x8  = (unsigned*)(ws + off); off += (size_t)n * F / 4;   // fp8 rows
    unsigned* x18 = (unsigned*)(ws + off); off += (size_t)n * F / 4;
    unsigned short* wbf   = (unsigned short*)(ws + off);
    size_t woff = 0;
    unsigned short* fWl1  = wbf + woff; woff += F * F;
    unsigned short* fWr1  = wbf + woff; woff += F * F;
    unsigned short* fWl2  = wbf + woff; woff += F * F;
    unsigned short* fWr2  = wbf + woff; woff += F * F;
    unsigned short* fs1w1 = wbf + woff; woff += F * FH;
    unsigned short* fs2w1 = wbf + woff; woff += F * FH;
    unsigned short* fs1w2 = wbf + woff; woff += FH * F;
    unsigned short* fs2w2 = wbf + woff; woff += FH * F;
    off += (woff + 1) / 2;
    int* iws = (int*)(ws + off);
    size_t ioff = 0;
    int* bcur  = iws + ioff; ioff += 1024;
    int* start = iws + ioff; ioff += n;
    int* deg   = iws + ioff; ioff += n;
    int* keys  = iws + ioff; ioff += (size_t)B * CAP;
    int* eid   = iws + ioff; ioff += (size_t)B * CAP;

    const int total4 = n * (F / 4);
    const int sblocks = (E + 16383) / 16384;
    const int ablocks = (n + 3) / 4;
    const int gblocks = (n + 63) / 64;
    const int nq = n * (F / 4);
    const int apblocks = (nq + 255) / 256;
    const float invn = 1.0f / (float)n;

    // ---- x -> bf16 + fp8 ----
    conv_dual_kernel<<<(total4 + 255) / 256, 256, 0, stream>>>(x, xb, x8, total4);

    // ---- CSR build ----
    bcur_init_kernel<<<4, 256, 0, stream>>>(bcur, B);
    scatter_block_kernel<<<sblocks, 1024, 0, stream>>>(src, dst, bcur, keys, E, B);
    bucket_sort_kernel<<<B, 256, 0, stream>>>(keys, bcur, eid, start, deg, n);

    // ---- weight prep ----
    PrepArgs pa;
    pa.s[0] = Wl1;  pa.d[0] = fWl1;
    pa.s[1] = Wr1;  pa.d[1] = fWr1;
    pa.s[2] = Wl2;  pa.d[2] = fWl2;
    pa.s[3] = Wr2;  pa.d[3] = fWr2;
    pa.s[4] = s1w1; pa.d[4] = fs1w1;
    pa.s[5] = s2w1; pa.d[5] = fs2w1;
    pa.s[6] = s1w2; pa.d[6] = fs1w2;
    pa.s[7] = s2w2; pa.d[7] = fs2w2;
    prep_all_kernel<<<384, 256, 0, stream>>>(pa);

    // ---- layer 1 ----
    hipMemsetAsync(csum, 0, 2 * F * sizeof(float), stream);
    aggregate_kernel<<<ablocks, 256, 0, stream>>>((const unsigned short*)x8, eid, start, deg,
                                                  (unsigned*)aggb, n);
    fused_gemm_mfma<<<gblocks, 256, 0, stream>>>(xb, aggb, fWl1, fWr1, fs1w1, fs1w2,
        bl1, s1b1, s1b2, yb, skipb, csum, csq, n);
    bn_finalize_kernel<<<1, F, 0, stream>>>(csum, csq, g1, be1, scl, shf, invn);
    apply_kernel<<<apblocks, 256, 0, stream>>>((const unsigned*)yb, (const unsigned*)skipb,
        scl, shf, (unsigned*)x1b, x18, nullptr, 0, nq);

    // ---- layer 2 ----
    hipMemsetAsync(csum, 0, 2 * F * sizeof(float), stream);
    aggregate_kernel<<<ablocks, 256, 0, stream>>>((const unsigned short*)x18, eid, start, deg,
                                                  (unsigned*)aggb, n);
    fused_gemm_mfma<<<gblocks, 256, 0, stream>>>(x1b, aggb, fWl2, fWr2, fs2w1, fs2w2,
        bl2, s2b1, s2b2, yb, skipb, csum, csq, n);
    bn_finalize_kernel<<<1, F, 0, stream>>>(csum, csq, g2, be2, scl, shf, invn);
    apply_kernel<<<apblocks, 256, 0, stream>>>((const unsigned*)yb, (const unsigned*)skipb,
        scl, shf, nullptr, nullptr, (float*)d_out, 1, nq);
}

// Round 8
// 442.588 us; speedup vs baseline: 1.4908x; 1.0226x over previous
//
#include <hip/hip_runtime.h>

// GraphSAGE round 8: occupancy diet for fused_gemm (h overlaid into xsf LDS,
// 33 KB -> 4 blocks/CU) + BN finalize folded into apply + single startup memset.
// Numerics identical to round 7 (fp8 gather, bf16 MFMA, fp32 accumulate).

#define F   128
#define FH  64
#define EPS 1e-5f
#define CAP 4096            // slots per bucket (avg fill 2046)
#define TSTR 132            // transpose LDS row stride in shorts (264 B, 8B-aligned)

typedef __attribute__((ext_vector_type(8))) short short8v;
typedef __attribute__((ext_vector_type(4))) short short4v;
typedef __attribute__((ext_vector_type(4))) float floatx4;
typedef __attribute__((ext_vector_type(2))) float floatx2;

__device__ inline unsigned short f2bf(float f) {
    unsigned u = __builtin_bit_cast(unsigned, f);
    u += 0x7fff + ((u >> 16) & 1);          // round-to-nearest-even
    return (unsigned short)(u >> 16);
}
__device__ inline float bflo(unsigned u) { return __builtin_bit_cast(float, u << 16); }
__device__ inline float bfhi(unsigned u) { return __builtin_bit_cast(float, u & 0xffff0000u); }

// ---------------- x -> bf16 + fp8 ----------------
__global__ __launch_bounds__(256) void conv_dual_kernel(
    const float* __restrict__ x, unsigned short* __restrict__ xb,
    unsigned* __restrict__ x8, int total4)
{
    int t = blockIdx.x * 256 + threadIdx.x;
    if (t >= total4) return;
    float4 v = reinterpret_cast<const float4*>(x)[t];
    short4v p = { (short)f2bf(v.x), (short)f2bf(v.y), (short)f2bf(v.z), (short)f2bf(v.w) };
    *reinterpret_cast<short4v*>(xb + t * 4) = p;
    unsigned p8 = __builtin_amdgcn_cvt_pk_fp8_f32(v.x, v.y, 0, false);
    p8 = __builtin_amdgcn_cvt_pk_fp8_f32(v.z, v.w, p8, true);
    x8[t] = p8;
}

// ---------------- CSR build ----------------
// bcur holds RELATIVE fill counts (zeroed by the startup memset); bases are b*CAP.
__global__ __launch_bounds__(1024) void scatter_block_kernel(
    const int* __restrict__ src, const int* __restrict__ dst,
    int* __restrict__ bcur, int* __restrict__ keys, int E, int B)
{
    __shared__ int hist[1024];
    __shared__ int lbase[1024];
    const int tid = threadIdx.x;
    const int e0 = blockIdx.x * 16384;
    const int e1 = min(e0 + 16384, E);
    hist[tid] = 0;
    __syncthreads();
    for (int e = e0 + tid; e < e1; e += 1024)
        atomicAdd(&hist[dst[e] >> 7], 1);          // LDS, non-returning
    __syncthreads();
    if (tid < B) {
        int c = hist[tid];
        lbase[tid] = (c > 0) ? (tid * CAP + atomicAdd(&bcur[tid], c)) : 0;
    }
    __syncthreads();
    hist[tid] = 0;
    __syncthreads();
    for (int e = e0 + tid; e < e1; e += 1024) {
        int d = dst[e];
        int b = d >> 7;
        int p = lbase[b] + atomicAdd(&hist[b], 1);  // LDS returning (fast)
        if (p < (b + 1) * CAP)                      // overflow guard
            keys[p] = (src[e] << 7) | (d & 127);
    }
}

__global__ __launch_bounds__(256) void bucket_sort_kernel(
    const int* __restrict__ keys, const int* __restrict__ bcur,
    int* __restrict__ eid, int* __restrict__ start, int* __restrict__ deg, int n)
{
    __shared__ int cnt[128], cur[128], sc[128];
    __shared__ int sorted[CAP];
    const int b = blockIdx.x;
    const int tid = threadIdx.x;
    const int base = b * CAP;
    int count = bcur[b];                 // relative fill
    if (count > CAP) count = CAP;
    const int v0 = b << 7;

    if (tid < 128) cnt[tid] = 0;
    __syncthreads();
    for (int i = tid; i < count; i += 256)
        atomicAdd(&cnt[keys[base + i] & 127], 1);
    __syncthreads();
    if (tid < 128) sc[tid] = cnt[tid];
    __syncthreads();
    for (int o = 1; o < 128; o <<= 1) {
        int a = (tid < 128 && tid >= o) ? sc[tid - o] : 0;
        __syncthreads();
        if (tid < 128) sc[tid] += a;
        __syncthreads();
    }
    if (tid < 128) {
        int excl = sc[tid] - cnt[tid];
        int v = v0 + tid;
        if (v < n) { start[v] = base + excl; deg[v] = cnt[tid]; }
        cur[tid] = excl;
    }
    __syncthreads();
    for (int i = tid; i < count; i += 256) {
        int k = keys[base + i];
        int p = atomicAdd(&cur[k & 127], 1);
        sorted[p] = k >> 7;
    }
    __syncthreads();
    for (int i = tid; i < count; i += 256) eid[base + i] = sorted[i];
}

// ---------------- gather aggregation (fp8 rows): agg[v] = mean x[N(v)] ------------
__global__ __launch_bounds__(256) void aggregate_kernel(
    const unsigned short* __restrict__ x8, const int* __restrict__ eid,
    const int* __restrict__ start, const int* __restrict__ deg,
    unsigned int* __restrict__ aggb2, int n)
{
    int w = (blockIdx.x * 256 + threadIdx.x) >> 6;
    int l = threadIdx.x & 63;
    if (w >= n) return;
    const int beg = start[w];
    const int c   = deg[w];
    float a0 = 0.f, a1 = 0.f, b0 = 0.f, b1 = 0.f;
    int off = beg, rem = c;
    while (rem > 0) {
        int m = rem < 64 ? rem : 64;
        int id = (l < m) ? eid[off + l] : 0;
        int j = 0;
        for (; j + 3 < m; j += 4) {
            int s0 = __shfl(id, j), s1 = __shfl(id, j + 1);
            int s2 = __shfl(id, j + 2), s3 = __shfl(id, j + 3);
            unsigned short u0 = x8[(size_t)s0 * 64 + l];
            unsigned short u1 = x8[(size_t)s1 * 64 + l];
            unsigned short u2 = x8[(size_t)s2 * 64 + l];
            unsigned short u3 = x8[(size_t)s3 * 64 + l];
            floatx2 f0 = __builtin_amdgcn_cvt_pk_f32_fp8((int)u0, false);
            floatx2 f1 = __builtin_amdgcn_cvt_pk_f32_fp8((int)u1, false);
            floatx2 f2 = __builtin_amdgcn_cvt_pk_f32_fp8((int)u2, false);
            floatx2 f3 = __builtin_amdgcn_cvt_pk_f32_fp8((int)u3, false);
            a0 += f0.x; a1 += f0.y;
            b0 += f1.x; b1 += f1.y;
            a0 += f2.x; a1 += f2.y;
            b0 += f3.x; b1 += f3.y;
        }
        for (; j < m; ++j) {
            int s0 = __shfl(id, j);
            unsigned short u0 = x8[(size_t)s0 * 64 + l];
            floatx2 f0 = __builtin_amdgcn_cvt_pk_f32_fp8((int)u0, false);
            a0 += f0.x; a1 += f0.y;
        }
        off += m; rem -= m;
    }
    float inv = 1.0f / fmaxf((float)c, 1.0f);
    float o0 = (a0 + b0) * inv, o1 = (a1 + b1) * inv;
    aggb2[(size_t)w * 64 + l] = (unsigned)f2bf(o0) | ((unsigned)f2bf(o1) << 16);
}

// ---------------- weight prep: fp32 [K][N] -> bf16 fragment order ----------------
struct PrepArgs { const float* s[8]; unsigned short* d[8]; };

__global__ __launch_bounds__(256) void prep_all_kernel(PrepArgs a)
{
    int t = blockIdx.x * 256 + threadIdx.x;
    int m, idx, K, N;
    if (t < 4 * 16384)            { m = t >> 14;                 idx = t & 16383; K = 128; N = 128; }
    else if (t < 4 * 16384 + 2 * 8192) { int u = t - 4 * 16384;  m = 4 + (u >> 13); idx = u & 8191; K = 128; N = 64; }
    else                          { int u = t - 4 * 16384 - 2 * 8192; if (u >= 2 * 8192) return;
                                    m = 6 + (u >> 13); idx = u & 8191; K = 64; N = 128; }
    int k = idx / N, c = idx % N;
    int ct = c >> 4, ks = k >> 5;
    int lane = (c & 15) + (((k & 31) >> 3) << 4);
    int j = k & 7;
    a.d[m][((ct * (K >> 5) + ks) * 64 + lane) * 8 + j] = f2bf(a.s[m][idx]);
}

// ---------------- fused MFMA GEMM, 33 KB LDS (h overlaid into xsf) ----------------
__global__ __launch_bounds__(256, 4) void fused_gemm_mfma(
    const unsigned short* __restrict__ xb, const unsigned short* __restrict__ aggb,
    const unsigned short* __restrict__ wlf, const unsigned short* __restrict__ wrf,
    const unsigned short* __restrict__ whf, const unsigned short* __restrict__ wsf,
    const float* __restrict__ bl, const float* __restrict__ sb1,
    const float* __restrict__ sb2,
    unsigned short* __restrict__ y, unsigned short* __restrict__ skip,
    float* __restrict__ colsum, float* __restrict__ colsq, int n)
{
    __shared__ unsigned short xsf[4 * 4 * 64 * 8];   // 16 KB: x frags, then h (64x88)
    __shared__ unsigned short abuf[64 * TSTR];       // 16.5 KB: agg frags, then transpose

    const int tid = threadIdx.x;
    const int r0 = blockIdx.x * 64;
    const int w = tid >> 6;
    const int l = tid & 63;

    // ---- stage x & agg tiles into frag-order LDS ----
    {
        const short8v zero8 = {0, 0, 0, 0, 0, 0, 0, 0};
        for (int i = tid; i < 64 * 16; i += 256) {
            int r = i >> 4, s = i & 15;
            int row = r0 + r;
            short8v vx = zero8, va = zero8;
            if (row < n) {
                vx = *reinterpret_cast<const short8v*>(xb + (size_t)row * F + s * 8);
                va = *reinterpret_cast<const short8v*>(aggb + (size_t)row * F + s * 8);
            }
            int rt = r >> 4, ks = s >> 2;
            int lslot = (r & 15) + ((s & 3) << 4);
            int off = ((rt * 4 + ks) * 64 + lslot) * 8;
            *(short8v*)&xsf[off] = vx;
            *(short8v*)&abuf[off] = va;
        }
    }

    // ---- register-resident B fragments ----
    const short8v* wl8 = (const short8v*)wlf;
    const short8v* wr8 = (const short8v*)wrf;
    const short8v* wh8 = (const short8v*)whf;
    const short8v* ws8 = (const short8v*)wsf;
    short8v bWl[2][4], bWr[2][4];
#pragma unroll
    for (int ct = 0; ct < 2; ++ct)
#pragma unroll
        for (int ks = 0; ks < 4; ++ks) {
            int idx = ((w * 2 + ct) * 4 + ks) * 64 + l;
            bWl[ct][ks] = wl8[idx];
            bWr[ct][ks] = wr8[idx];
        }
    short8v bh[4];
#pragma unroll
    for (int ks = 0; ks < 4; ++ks) bh[ks] = wh8[(w * 4 + ks) * 64 + l];
    short8v bs[2][2];
#pragma unroll
    for (int ct = 0; ct < 2; ++ct)
#pragma unroll
        for (int ks = 0; ks < 2; ++ks)
            bs[ct][ks] = ws8[((w * 2 + ct) * 2 + ks) * 64 + l];

    __syncthreads();

    const short8v* xs8 = (const short8v*)xsf;
    const short8v* as8 = (const short8v*)abuf;
    const int col0 = w * 32 + (l & 15);
    const float bias0 = bl[col0], bias1 = bl[col0 + 16];

    // ---- phase Y: MFMAs; keep packed results in regs ----
    unsigned ypk[4][4];
    float psum0 = 0.f, psq0 = 0.f, psum1 = 0.f, psq1 = 0.f;
#pragma unroll
    for (int rt = 0; rt < 4; ++rt) {
        floatx4 acc0 = {0.f, 0.f, 0.f, 0.f};
        floatx4 acc1 = {0.f, 0.f, 0.f, 0.f};
#pragma unroll
        for (int ks = 0; ks < 4; ++ks) {
            short8v ax = xs8[(rt * 4 + ks) * 64 + l];
            short8v aa = as8[(rt * 4 + ks) * 64 + l];
            acc0 = __builtin_amdgcn_mfma_f32_16x16x32_bf16(aa, bWl[0][ks], acc0, 0, 0, 0);
            acc0 = __builtin_amdgcn_mfma_f32_16x16x32_bf16(ax, bWr[0][ks], acc0, 0, 0, 0);
            acc1 = __builtin_amdgcn_mfma_f32_16x16x32_bf16(aa, bWl[1][ks], acc1, 0, 0, 0);
            acc1 = __builtin_amdgcn_mfma_f32_16x16x32_bf16(ax, bWr[1][ks], acc1, 0, 0, 0);
        }
        int rowb = r0 + rt * 16 + (l >> 4) * 4;
#pragma unroll
        for (int reg = 0; reg < 4; ++reg) {
            int row = rowb + reg;
            float v0 = acc0[reg] + bias0;
            float v1 = acc1[reg] + bias1;
            ypk[rt][reg] = (unsigned)f2bf(v0) | ((unsigned)f2bf(v1) << 16);
            if (row < n) {
                psum0 += v0; psq0 += v0 * v0;
                psum1 += v1; psq1 += v1 * v1;
            }
        }
    }
    psum0 += __shfl_xor(psum0, 16); psum0 += __shfl_xor(psum0, 32);
    psq0  += __shfl_xor(psq0, 16);  psq0  += __shfl_xor(psq0, 32);
    psum1 += __shfl_xor(psum1, 16); psum1 += __shfl_xor(psum1, 32);
    psq1  += __shfl_xor(psq1, 16);  psq1  += __shfl_xor(psq1, 32);
    if (l < 16) {
        unsafeAtomicAdd(&colsum[col0], psum0);
        unsafeAtomicAdd(&colsq[col0], psq0);
        unsafeAtomicAdd(&colsum[col0 + 16], psum1);
        unsafeAtomicAdd(&colsq[col0 + 16], psq1);
    }

    // ---- phase H MFMAs -> registers only ----
    const int hcol = w * 16 + (l & 15);
    const float hbias = sb1[hcol];
    float hval[4][4];
#pragma unroll
    for (int rt = 0; rt < 4; ++rt) {
        floatx4 hacc = {0.f, 0.f, 0.f, 0.f};
#pragma unroll
        for (int ks = 0; ks < 4; ++ks) {
            short8v ax = xs8[(rt * 4 + ks) * 64 + l];
            hacc = __builtin_amdgcn_mfma_f32_16x16x32_bf16(ax, bh[ks], hacc, 0, 0, 0);
        }
#pragma unroll
        for (int reg = 0; reg < 4; ++reg) hval[rt][reg] = hacc[reg];
    }
    __syncthreads();   // all xsf/abuf frag reads retired

    // ---- write h into xsf region (64x88 row-major) + y transpose into abuf ----
#pragma unroll
    for (int rt = 0; rt < 4; ++rt) {
        int rowb = rt * 16 + (l >> 4) * 4;
#pragma unroll
        for (int reg = 0; reg < 4; ++reg) {
            xsf[(rowb + reg) * 88 + hcol] = f2bf(fmaxf(hval[rt][reg] + hbias, 0.f));
            abuf[(rowb + reg) * TSTR + col0]      = (unsigned short)(ypk[rt][reg] & 0xffff);
            abuf[(rowb + reg) * TSTR + col0 + 16] = (unsigned short)(ypk[rt][reg] >> 16);
        }
    }
    __syncthreads();

    // ---- phase S MFMAs (reads h from xsf) + coalesced y store (reads abuf) ----
    unsigned spk[4][4];
    const float sbias0 = sb2[col0], sbias1 = sb2[col0 + 16];
#pragma unroll
    for (int rt = 0; rt < 4; ++rt) {
        floatx4 s0 = {0.f, 0.f, 0.f, 0.f};
        floatx4 s1 = {0.f, 0.f, 0.f, 0.f};
#pragma unroll
        for (int ks = 0; ks < 2; ++ks) {
            short8v ah = *(const short8v*)&xsf[(rt * 16 + (l & 15)) * 88 + ks * 32 + (l >> 4) * 8];
            s0 = __builtin_amdgcn_mfma_f32_16x16x32_bf16(ah, bs[0][ks], s0, 0, 0, 0);
            s1 = __builtin_amdgcn_mfma_f32_16x16x32_bf16(ah, bs[1][ks], s1, 0, 0, 0);
        }
#pragma unroll
        for (int reg = 0; reg < 4; ++reg)
            spk[rt][reg] = (unsigned)f2bf(s0[reg] + sbias0) |
                           ((unsigned)f2bf(s1[reg] + sbias1) << 16);
    }
    {
        int row = tid & 63, ch = tid >> 6;
        if (r0 + row < n) {
            const uint2* srcp = (const uint2*)&abuf[row * TSTR + ch * 32];
            uint4* dst = (uint4*)(y + (size_t)(r0 + row) * F + ch * 32);
#pragma unroll
            for (int q = 0; q < 4; ++q) {
                uint2 a = srcp[2 * q], b2 = srcp[2 * q + 1];
                dst[q] = make_uint4(a.x, a.y, b2.x, b2.y);
            }
        }
    }
    __syncthreads();   // y-store abuf reads retired

    // ---- skip transpose -> abuf ----
#pragma unroll
    for (int rt = 0; rt < 4; ++rt) {
        int rowb = rt * 16 + (l >> 4) * 4;
#pragma unroll
        for (int reg = 0; reg < 4; ++reg) {
            abuf[(rowb + reg) * TSTR + col0]      = (unsigned short)(spk[rt][reg] & 0xffff);
            abuf[(rowb + reg) * TSTR + col0 + 16] = (unsigned short)(spk[rt][reg] >> 16);
        }
    }
    __syncthreads();

    // ---- coalesced skip store ----
    {
        int row = tid & 63, ch = tid >> 6;
        if (r0 + row < n) {
            const uint2* srcp = (const uint2*)&abuf[row * TSTR + ch * 32];
            uint4* dst = (uint4*)(skip + (size_t)(r0 + row) * F + ch * 32);
#pragma unroll
            for (int q = 0; q < 4; ++q) {
                uint2 a = srcp[2 * q], b2 = srcp[2 * q + 1];
                dst[q] = make_uint4(a.x, a.y, b2.x, b2.y);
            }
        }
    }
}

// ---------------- apply: inline BN finalize + relu(y*scale+shift+skip) ----------------
// layer-1 mode: writes x1 bf16 + x1 fp8.  layer-2 mode: writes fp32 d_out.
__global__ __launch_bounds__(256) void apply_kernel(
    const unsigned int* __restrict__ y2, const unsigned int* __restrict__ s2,
    const float* __restrict__ csum, const float* __restrict__ csq,
    const float* __restrict__ g, const float* __restrict__ beta,
    unsigned int* __restrict__ out_bf, unsigned int* __restrict__ out_f8,
    float* __restrict__ out_f32, int out_fp32, float invn, int nq)
{
    int t = blockIdx.x * 256 + threadIdx.x;
    if (t >= nq) return;
    int jq = t & 31;
    float4 cs = reinterpret_cast<const float4*>(csum)[jq];
    float4 cq = reinterpret_cast<const float4*>(csq)[jq];
    float4 gg = reinterpret_cast<const float4*>(g)[jq];
    float4 bb = reinterpret_cast<const float4*>(beta)[jq];
    float mu0 = cs.x * invn, mu1 = cs.y * invn, mu2 = cs.z * invn, mu3 = cs.w * invn;
    float sc0 = rsqrtf(cq.x * invn - mu0 * mu0 + EPS) * gg.x;
    float sc1 = rsqrtf(cq.y * invn - mu1 * mu1 + EPS) * gg.y;
    float sc2 = rsqrtf(cq.z * invn - mu2 * mu2 + EPS) * gg.z;
    float sc3 = rsqrtf(cq.w * invn - mu3 * mu3 + EPS) * gg.w;
    float sh0 = bb.x - mu0 * sc0;
    float sh1 = bb.y - mu1 * sc1;
    float sh2 = bb.z - mu2 * sc2;
    float sh3 = bb.w - mu3 * sc3;

    uint2 yv = reinterpret_cast<const uint2*>(y2)[t];
    uint2 sv = reinterpret_cast<const uint2*>(s2)[t];
    float o0 = fmaxf(bflo(yv.x) * sc0 + sh0 + bflo(sv.x), 0.f);
    float o1 = fmaxf(bfhi(yv.x) * sc1 + sh1 + bfhi(sv.x), 0.f);
    float o2 = fmaxf(bflo(yv.y) * sc2 + sh2 + bflo(sv.y), 0.f);
    float o3 = fmaxf(bfhi(yv.y) * sc3 + sh3 + bfhi(sv.y), 0.f);
    if (out_fp32) {
        reinterpret_cast<float4*>(out_f32)[t] = make_float4(o0, o1, o2, o3);
    } else {
        uint2 p;
        p.x = (unsigned)f2bf(o0) | ((unsigned)f2bf(o1) << 16);
        p.y = (unsigned)f2bf(o2) | ((unsigned)f2bf(o3) << 16);
        reinterpret_cast<uint2*>(out_bf)[t] = p;
        unsigned p8 = __builtin_amdgcn_cvt_pk_fp8_f32(o0, o1, 0, false);
        p8 = __builtin_amdgcn_cvt_pk_fp8_f32(o2, o3, p8, true);
        out_f8[t] = p8;
    }
}

extern "C" void kernel_launch(void* const* d_in, const int* in_sizes, int n_in,
                              void* d_out, int out_size, void* d_ws, size_t ws_size,
                              hipStream_t stream)
{
    const float* x    = (const float*)d_in[0];
    const int*   ei   = (const int*)d_in[1];
    const float* Wl1  = (const float*)d_in[2];
    const float* bl1  = (const float*)d_in[3];
    const float* Wr1  = (const float*)d_in[4];
    const float* Wl2  = (const float*)d_in[5];
    const float* bl2  = (const float*)d_in[6];
    const float* Wr2  = (const float*)d_in[7];
    const float* s1w1 = (const float*)d_in[8];
    const float* s1b1 = (const float*)d_in[9];
    const float* s1w2 = (const float*)d_in[10];
    const float* s1b2 = (const float*)d_in[11];
    const float* s2w1 = (const float*)d_in[12];
    const float* s2b1 = (const float*)d_in[13];
    const float* s2w2 = (const float*)d_in[14];
    const float* s2b2 = (const float*)d_in[15];
    const float* g1   = (const float*)d_in[16];
    const float* be1  = (const float*)d_in[17];
    const float* g2   = (const float*)d_in[18];
    const float* be2  = (const float*)d_in[19];

    const int n = in_sizes[0] / F;       // 100000
    const int E = in_sizes[1] / 2;       // 1600000
    const int* src = ei;
    const int* dst = ei + E;
    const int B = (n + 127) >> 7;        // 782 buckets

    // ---- workspace carve-up (float units) ----
    // [stats: csum1 csq1 csum2 csq2 (512 floats)] [bcur (1024 ints)] -- one memset
    float* ws = (float*)d_ws;
    size_t off = 0;
    float* csum1 = ws + off; off += F;
    float* csq1  = ws + off; off += F;
    float* csum2 = ws + off; off += F;
    float* csq2  = ws + off; off += F;
    int* bcur = (int*)(ws + off); off += 1024;
    unsigned short* xb    = (unsigned short*)(ws + off); off += (size_t)n * F / 2;
    unsigned short* x1b   = (unsigned short*)(ws + off); off += (size_t)n * F / 2;
    unsigned short* yb    = (unsigned short*)(ws + off); off += (size_t)n * F / 2;
    unsigned short* skipb = (unsigned short*)(ws + off); off += (size_t)n * F / 2;
    unsigned short* aggb  = (unsigned short*)(ws + off); off += (size_t)n * F / 2;
    unsigned* x8  = (unsigned*)(ws + off); off += (size_t)n * F / 4;   // fp8 rows
    unsigned* x18 = (unsigned*)(ws + off); off += (size_t)n * F / 4;
    unsigned short* wbf   = (unsigned short*)(ws + off);
    size_t woff = 0;
    unsigned short* fWl1  = wbf + woff; woff += F * F;
    unsigned short* fWr1  = wbf + woff; woff += F * F;
    unsigned short* fWl2  = wbf + woff; woff += F * F;
    unsigned short* fWr2  = wbf + woff; woff += F * F;
    unsigned short* fs1w1 = wbf + woff; woff += F * FH;
    unsigned short* fs2w1 = wbf + woff; woff += F * FH;
    unsigned short* fs1w2 = wbf + woff; woff += FH * F;
    unsigned short* fs2w2 = wbf + woff; woff += FH * F;
    off += (woff + 1) / 2;
    int* iws = (int*)(ws + off);
    size_t ioff = 0;
    int* start = iws + ioff; ioff += n;
    int* deg   = iws + ioff; ioff += n;
    int* keys  = iws + ioff; ioff += (size_t)B * CAP;
    int* eid   = iws + ioff; ioff += (size_t)B * CAP;

    const int total4 = n * (F / 4);
    const int sblocks = (E + 16383) / 16384;
    const int ablocks = (n + 3) / 4;
    const int gblocks = (n + 63) / 64;
    const int nq = n * (F / 4);
    const int apblocks = (nq + 255) / 256;
    const float invn = 1.0f / (float)n;

    // ---- single startup memset: stats (2 KB) + bcur (4 KB) ----
    hipMemsetAsync(ws, 0, 512 * sizeof(float) + 1024 * sizeof(int), stream);

    // ---- x -> bf16 + fp8 ----
    conv_dual_kernel<<<(total4 + 255) / 256, 256, 0, stream>>>(x, xb, x8, total4);

    // ---- CSR build ----
    scatter_block_kernel<<<sblocks, 1024, 0, stream>>>(src, dst, bcur, keys, E, B);
    bucket_sort_kernel<<<B, 256, 0, stream>>>(keys, bcur, eid, start, deg, n);

    // ---- weight prep ----
    PrepArgs pa;
    pa.s[0] = Wl1;  pa.d[0] = fWl1;
    pa.s[1] = Wr1;  pa.d[1] = fWr1;
    pa.s[2] = Wl2;  pa.d[2] = fWl2;
    pa.s[3] = Wr2;  pa.d[3] = fWr2;
    pa.s[4] = s1w1; pa.d[4] = fs1w1;
    pa.s[5] = s2w1; pa.d[5] = fs2w1;
    pa.s[6] = s1w2; pa.d[6] = fs1w2;
    pa.s[7] = s2w2; pa.d[7] = fs2w2;
    prep_all_kernel<<<384, 256, 0, stream>>>(pa);

    // ---- layer 1 ----
    aggregate_kernel<<<ablocks, 256, 0, stream>>>((const unsigned short*)x8, eid, start, deg,
                                                  (unsigned*)aggb, n);
    fused_gemm_mfma<<<gblocks, 256, 0, stream>>>(xb, aggb, fWl1, fWr1, fs1w1, fs1w2,
        bl1, s1b1, s1b2, yb, skipb, csum1, csq1, n);
    apply_kernel<<<apblocks, 256, 0, stream>>>((const unsigned*)yb, (const unsigned*)skipb,
        csum1, csq1, g1, be1, (unsigned*)x1b, x18, nullptr, 0, invn, nq);

    // ---- layer 2 ----
    aggregate_kernel<<<ablocks, 256, 0, stream>>>((const unsigned short*)x18, eid, start, deg,
                                                  (unsigned*)aggb, n);
    fused_gemm_mfma<<<gblocks, 256, 0, stream>>>(x1b, aggb, fWl2, fWr2, fs2w1, fs2w2,
        bl2, s2b1, s2b2, yb, skipb, csum2, csq2, n);
    apply_kernel<<<apblocks, 256, 0, stream>>>((const unsigned*)yb, (const unsigned*)skipb,
        csum2, csq2, g2, be2, nullptr, nullptr, (float*)d_out, 1, invn, nq);
}